// Round 5
// baseline (605.885 us; speedup 1.0000x reference)
//
#include <hip/hip_runtime.h>
#include <hip/hip_bf16.h>

typedef __attribute__((ext_vector_type(8))) short short8;
typedef __attribute__((ext_vector_type(4))) float fvec4;

#define NW 64
#define NN 144
#define CC 192
#define NH 6
#define LL 32
#define NLON 15
#define TT (NLON*NW*NN)   // 138240

// Pre-transformed weights in device-global memory (written by prep kernels).
__device__ ushort g_WF[6 * 36 * 512];    // per-head frag-linear qkv W  [h][kk6][nt6][lane][8]
__device__ ushort g_PF[6 * 12 * 512];    // frag-linear proj W          [kk6][nt12][lane][8]
__device__ __align__(4) ushort g_BC[64 * 6 * 3312];   // bias_table transposed [w][h][epi]

__device__ __forceinline__ float bf2f(ushort v) {
  union { unsigned int u; float f; } x;
  x.u = ((unsigned int)v) << 16;
  return x.f;
}
__device__ __forceinline__ ushort f2bf(float f) {
  union { float f; unsigned int u; } x; x.f = f;
  unsigned int r = (x.u + 0x7FFFu + ((x.u >> 16) & 1u)) >> 16;
  return (ushort)r;
}
// packed f32x2 -> bf16x2 (compiler emits v_cvt_pk_bf16_f32; RNE, matches f2bf)
__device__ __forceinline__ uint pack2(float a, float b) {
  __hip_bfloat162 t = __float22bfloat162_rn(make_float2(a, b));
  uint u; __builtin_memcpy(&u, &t, 4); return u;
}

// Robust dtype detector (needs arrays >= ~16KB; only used on large arrays).
__device__ bool arr_is_f32(const void* p) {
  const ushort* u = (const ushort*)p;
  int sane = 0;
#pragma unroll
  for (int k = 0; k < 16; ++k) {
    float v = bf2f(u[k * 514]);
    if (__builtin_fabsf(v) < 64.f) ++sane;
  }
  return sane < 16;
}
__device__ __forceinline__ float loadS(const void* p, size_t i, bool f) {
  return f ? ((const float*)p)[i] : bf2f(((const ushort*)p)[i]);
}

// ---------------------------------------------------------------------------
// prep_w: one-time weight reorganization (small: 147K elements). Idempotent.
__global__ __launch_bounds__(256) void prep_w(const void* __restrict__ qkv_w,
                                              const void* __restrict__ proj_w) {
  const bool wf = arr_is_f32(qkv_w);
  const bool pwf = arr_is_f32(proj_w);
  const int stride = gridDim.x * blockDim.x;
  const int t0 = blockIdx.x * blockDim.x + threadIdx.x;
  // WF: B-fragment value for (h,kk,nt): row c=nt*16+(lane&15), k=kk*32+(lane>>4)*8+j
  for (int i = t0; i < 6 * 36 * 512; i += stride) {
    int j = i & 7, lane = (i >> 3) & 63, f = i >> 9;   // f = h*36 + kk*6 + nt
    int nt = f % 6, kk = (f / 6) % 6, h = f / 36;
    int c = nt * 16 + (lane & 15);
    int k = kk * 32 + (lane >> 4) * 8 + j;
    int grow = (c >> 5) * 192 + h * 32 + (c & 31);
    g_WF[i] = f2bf(loadS(qkv_w, (size_t)grow * 192 + k, wf));
  }
  // PF: row c = nt*16+(lane&15) of proj_w, k = kk*32+(lane>>4)*8+j
  for (int i = t0; i < 6 * 12 * 512; i += stride) {
    int j = i & 7, lane = (i >> 3) & 63, f = i >> 9;   // f = kk*12 + nt
    int nt = f % 12, kk = f / 12;
    int c = nt * 16 + (lane & 15);
    int k = kk * 32 + (lane >> 4) * 8 + j;
    g_PF[i] = f2bf(loadS(proj_w, (size_t)c * 192 + k, pwf));
  }
}

// ---------------------------------------------------------------------------
// prep_bc: LDS-tiled transpose g_BC[wh][e] <- bt[e][wh]. 69 blocks x 48-e tile.
// Reads coalesced over wh; writes coalesced 96B-runs over e. (Round-4's
// grid-stride version did 1.27M isolated 2B scatter-writes at 6624B stride ->
// ~80MB of RMW sector traffic; this is the fix.)
__global__ __launch_bounds__(256) void prep_bc(const void* __restrict__ bt) {
  __shared__ ushort T[48 * 385];               // +1-ushort pad per row
  const bool bf = arr_is_f32(bt);
  const int e0 = blockIdx.x * 48;
  const int tid = threadIdx.x;
  for (int idx = tid; idx < 48 * 384; idx += 256) {
    int de = idx / 384, wh = idx - de * 384;   // consecutive tid -> consecutive wh
    T[de * 385 + wh] = f2bf(loadS(bt, (size_t)(e0 + de) * 384 + wh, bf));
  }
  __syncthreads();
  for (int idx = tid; idx < 48 * 384; idx += 256) {
    int wh = idx / 48, e2 = idx - wh * 48;     // consecutive tid -> consecutive e
    g_BC[(size_t)wh * 3312 + e0 + e2] = T[e2 * 385 + wh];
  }
}

// ---------------------------------------------------------------------------
// MFMA fused QKV + attention, SWAPPED-operand phase 2 (S^T = mfma(K,Q)):
// thread (l15,lg) owns query col n=wv*16+l15, key rows {m: (m&15)>>2 == lg}.
// Softmax max/sum reduce across the 4-lane group via __shfl_xor(16|32).
// One block per (b,w,h); 9 waves, one 16-token strip each.
// LDS map (29248 B):
//  [0,9216)      qF [9 strip][64][16B]  q*scale bf16; wave's own slot reused as
//                                       P-redistribution scratch in phase 2
//  [9216,18432)  kF [9 tile ][64][16B]  bf16
//  [18432,28672) vF [10 blk=(tk*2+dh)][64][16B]  v^T, tokens 144..159 zeroed
//  [28672,29248) em_tab int[144]  (bias m-offset table)
// Occupancy: 9-wave blocks -> (576,5) cap102 and (576,6) cap85 BOTH give
// 2 blocks/CU, but cap85 spilled 4 VGPRs (round-4 WRITE_SIZE 155MB vs 103.7MB
// output; cap102 rounds 1-2 wrote exactly 103.7MB). Use cap102.
__global__ __launch_bounds__(576, 5) void attn_mfma(
    const void* __restrict__ x, const void* __restrict__ qkv_w,
    const void* __restrict__ qkv_b, const void* __restrict__ mask,
    float* __restrict__ out) {
  __shared__ __attribute__((aligned(16))) char lds[29248];
  const bool xf = arr_is_f32(x);
  const bool wf = arr_is_f32(qkv_w);   // qkv_b shares policy
  // XCD-chunked swizzle: 5760 blocks, 8 XCDs, 720/chunk (bijective).
  const int i0 = blockIdx.x;
  const int ii = (i0 & 7) * 720 + (i0 >> 3);
  const int h = ii % 6;
  const int g0 = ii / 6;
  const int w = g0 & 63, bb = g0 >> 6;
  const int tid = threadIdx.x;
  const int lane = tid & 63, wv = tid >> 6;
  const int l15 = lane & 15, lg = lane >> 4;
  const size_t tok0 = ((size_t)bb * NW + w) * NN;

  // ---- preload x A-fragments (6 K-steps of 32) for this wave's strip
  short8 afr[6];
  {
    const size_t xrow = (tok0 + wv * 16 + l15) * CC + lg * 8;
    if (xf) {
      const float* xp = (const float*)x + xrow;
#pragma unroll
      for (int kk = 0; kk < 6; ++kk) {
        fvec4 a = *(const fvec4*)(xp + kk * 32);
        fvec4 b = *(const fvec4*)(xp + kk * 32 + 4);
        union { uint4 u; short8 s; } cv;
        cv.u = make_uint4(pack2(a[0], a[1]), pack2(a[2], a[3]),
                          pack2(b[0], b[1]), pack2(b[2], b[3]));
        afr[kk] = cv.s;
      }
    } else {
      const ushort* xp = (const ushort*)x + xrow;
#pragma unroll
      for (int kk = 0; kk < 6; ++kk) afr[kk] = *(const short8*)(xp + kk * 32);
    }
  }
  // ---- zero vT token-tail (tokens 144..159 of the 160-padded PV K dim)
  if (tid < 256) {
    int half = tid >> 7, off = tid & 127;
    ((uint*)(lds + 18432 + (8 + half) * 1024 + 512))[off] = 0;
  }
  // ---- em table: bias m-offset, em[m] = 1656*z2 + 138*h2 - w2
  if (tid < 144) {
    int z2 = tid / 72, r2 = tid - z2 * 72;
    int h2 = r2 / 12, w2 = r2 - h2 * 12;
    ((int*)(lds + 28672))[tid] = 1656 * z2 + 138 * h2 - w2;
  }

  // ---- phase 1: per-head QKV GEMM [144x192]@[192x96], 36 MFMAs/wave
  fvec4 acc[6];
#pragma unroll
  for (int nt = 0; nt < 6; ++nt) acc[nt] = (fvec4){0.f, 0.f, 0.f, 0.f};
  {
    const short8* WFp = (const short8*)g_WF + (size_t)h * 36 * 64;
#pragma unroll
    for (int kk = 0; kk < 6; ++kk) {
#pragma unroll
      for (int nt = 0; nt < 6; ++nt) {
        short8 b = WFp[(kk * 6 + nt) * 64 + lane];
        acc[nt] = __builtin_amdgcn_mfma_f32_16x16x32_bf16(afr[kk], b, acc[nt], 0, 0, 0);
      }
    }
  }
  // add qkv bias, pre-scale q by 1/sqrt(32), scatter to fragment-linear q/k/vT
#pragma unroll
  for (int nt = 0; nt < 6; ++nt) {
    int c = nt * 16 + l15;
    int which = c >> 5, dim = c & 31;
    float bv = loadS(qkv_b, which * 192 + h * 32 + dim, wf);
#pragma unroll
    for (int r = 0; r < 4; ++r) {
      float v = acc[nt][r] + bv;
      int t15 = lg * 4 + r;                        // token & 15
      if (nt < 2) {
        v *= 0.17677669529663687f;
        *(ushort*)(lds + wv * 1024 + ((dim >> 3) << 8) + (t15 << 4) + ((dim & 7) << 1)) = f2bf(v);
      } else if (nt < 4) {
        *(ushort*)(lds + 9216 + wv * 1024 + ((dim >> 3) << 8) + (t15 << 4) + ((dim & 7) << 1)) = f2bf(v);
      } else {
        int t = wv * 16 + t15;
        *(ushort*)(lds + 18432 + (((t >> 5) * 2 + (dim >> 4)) << 10) +
                   (((t >> 3) & 3) << 8) + ((dim & 15) << 4) + ((t & 7) << 1)) = f2bf(v);
      }
    }
  }
  __syncthreads();   // the only barrier

  // ---- phase 2 (swapped): thread owns query col n = wv*16 + l15.
  const short8* qf8 = (const short8*)lds;
  const short8* kf8 = (const short8*)(lds + 9216);
  const short8* vf8 = (const short8*)(lds + 18432);
  const int* emt = (const int*)(lds + 28672);
  const ushort* bc = g_BC + (size_t)(w * 6 + h) * 3312;
  short8 qfr = qf8[wv * 64 + lane];          // wave's q slot now dead -> P scratch

  const int n_glob = wv * 16 + l15;
  int en;
  {
    int z1 = n_glob / 72, r1 = n_glob - z1 * 72;
    int h1 = r1 / 12, w1 = r1 - h1 * 12;
    en = 828 * z1 + 23 * h1 + w1 + 11;
  }
  const size_t mrow = (tok0 + n_glob) * (size_t)NN;

  // S^T tile for key-tile mt: rows m = mt*16+lg*4+r, col n. C = bias+mask.
  auto qk_tile = [&](int mt) -> fvec4 {
    int4 ev = *(const int4*)(emt + mt * 16 + lg * 4);
    fvec4 cc;
    if (xf) {
      cc = *(const fvec4*)((const float*)mask + mrow + mt * 16 + lg * 4);
    } else {
      const ushort* mp = (const ushort*)mask + mrow + mt * 16 + lg * 4;
      cc[0] = bf2f(mp[0]); cc[1] = bf2f(mp[1]); cc[2] = bf2f(mp[2]); cc[3] = bf2f(mp[3]);
    }
    cc[0] += bf2f(bc[en + ev.x]);
    cc[1] += bf2f(bc[en + ev.y]);
    cc[2] += bf2f(bc[en + ev.z]);
    cc[3] += bf2f(bc[en + ev.w]);
    return __builtin_amdgcn_mfma_f32_16x16x32_bf16(kf8[mt * 64 + lane], qfr, cc, 0, 0, 0);
  };

  char* ps = lds + wv * 1024;                 // wave-private P scratch (1KB)
  const int wo0 = ((((lg >> 1)) * 16 + l15) << 4) + ((lg & 1) << 3);      // parity 0
  const int wo1 = ((((lg >> 1) + 2) * 16 + l15) << 4) + ((lg & 1) << 3);  // parity 1
  float mrun, sum = 0.f;
  fvec4 o0 = {0.f, 0.f, 0.f, 0.f}, o1 = {0.f, 0.f, 0.f, 0.f};

  // ===== chunk A: key tiles mt 0..3 (tk 0..1) =====
  {
    fvec4 sa[4];
#pragma unroll
    for (int i = 0; i < 4; ++i) sa[i] = qk_tile(i);
    float mx = fmaxf(fmaxf(sa[0][0], sa[0][1]), fmaxf(sa[0][2], sa[0][3]));
#pragma unroll
    for (int i = 1; i < 4; ++i)
      mx = fmaxf(mx, fmaxf(fmaxf(sa[i][0], sa[i][1]), fmaxf(sa[i][2], sa[i][3])));
    // group reduction: all 4 lanes holding query n must share one max
    mx = fmaxf(mx, __shfl_xor(mx, 16));
    mx = fmaxf(mx, __shfl_xor(mx, 32));
    mrun = mx;
#pragma unroll
    for (int i = 0; i < 4; ++i)
#pragma unroll
      for (int r = 0; r < 4; ++r) {
        float e = __expf(sa[i][r] - mx);
        sa[i][r] = e;
        sum += e;                              // per-thread partial; reduced at end
      }
    uint pw[8];
#pragma unroll
    for (int i = 0; i < 4; ++i) {
      pw[2 * i]     = pack2(sa[i][0], sa[i][1]);
      pw[2 * i + 1] = pack2(sa[i][2], sa[i][3]);
    }
#pragma unroll
    for (int tk = 0; tk < 2; ++tk) {
      *(uint2*)(ps + wo0) = make_uint2(pw[4 * tk + 0], pw[4 * tk + 1]);   // mt=2tk
      *(uint2*)(ps + wo1) = make_uint2(pw[4 * tk + 2], pw[4 * tk + 3]);   // mt=2tk+1
      short8 pfr = *(const short8*)(ps + lane * 16);
      o0 = __builtin_amdgcn_mfma_f32_16x16x32_bf16(vf8[(tk * 2 + 0) * 64 + lane], pfr, o0, 0, 0, 0);
      o1 = __builtin_amdgcn_mfma_f32_16x16x32_bf16(vf8[(tk * 2 + 1) * 64 + lane], pfr, o1, 0, 0, 0);
    }
  }
  // ===== chunk B: key tiles mt 4..8 (tk 2..4), online rescale =====
  {
    fvec4 sb[5];
#pragma unroll
    for (int i = 0; i < 5; ++i) sb[i] = qk_tile(4 + i);
    float lmx = fmaxf(fmaxf(sb[0][0], sb[0][1]), fmaxf(sb[0][2], sb[0][3]));
#pragma unroll
    for (int i = 1; i < 5; ++i)
      lmx = fmaxf(lmx, fmaxf(fmaxf(sb[i][0], sb[i][1]), fmaxf(sb[i][2], sb[i][3])));
    lmx = fmaxf(lmx, __shfl_xor(lmx, 16));
    lmx = fmaxf(lmx, __shfl_xor(lmx, 32));
    float mx = fmaxf(mrun, lmx);               // group-uniform (mrun uniform too)
    float al = __expf(mrun - mx);
    sum *= al;
#pragma unroll
    for (int r = 0; r < 4; ++r) { o0[r] *= al; o1[r] *= al; }
#pragma unroll
    for (int i = 0; i < 5; ++i)
#pragma unroll
      for (int r = 0; r < 4; ++r) {
        float e = __expf(sb[i][r] - mx);
        sb[i][r] = e;
        sum += e;
      }
    mrun = mx;
    uint pw[12];
#pragma unroll
    for (int i = 0; i < 5; ++i) {
      pw[2 * i]     = pack2(sb[i][0], sb[i][1]);
      pw[2 * i + 1] = pack2(sb[i][2], sb[i][3]);
    }
    pw[10] = 0; pw[11] = 0;                    // key tokens 144..159
#pragma unroll
    for (int ti = 0; ti < 3; ++ti) {
      int tk = ti + 2;
      *(uint2*)(ps + wo0) = make_uint2(pw[4 * ti + 0], pw[4 * ti + 1]);
      *(uint2*)(ps + wo1) = make_uint2(pw[4 * ti + 2], pw[4 * ti + 3]);
      short8 pfr = *(const short8*)(ps + lane * 16);
      o0 = __builtin_amdgcn_mfma_f32_16x16x32_bf16(vf8[(tk * 2 + 0) * 64 + lane], pfr, o0, 0, 0, 0);
      o1 = __builtin_amdgcn_mfma_f32_16x16x32_bf16(vf8[(tk * 2 + 1) * 64 + lane], pfr, o1, 0, 0, 0);
    }
  }
  // epilogue: full softmax denominator for query n = group-reduced sum
  sum += __shfl_xor(sum, 16);
  sum += __shfl_xor(sum, 32);
  float inv = 1.f / sum;
  fvec4 r0, r1;
#pragma unroll
  for (int r = 0; r < 4; ++r) { r0[r] = o0[r] * inv; r1[r] = o1[r] * inv; }
  float* op = out + (tok0 + n_glob) * CC + h * LL + lg * 4;
  *(fvec4*)op = r0;
  *(fvec4*)(op + 16) = r1;
}

// ---------------------------------------------------------------------------
// MFMA in-place projection, swapped operands: D'[c][t] = mfma(W_frag, act_frag).
// 256 thr = 4 waves; wave owns 16 rows; fvec4 stores. No LDS, no barriers.
__global__ __launch_bounds__(256, 5) void proj_mfma(float* __restrict__ io,
                                                    const void* __restrict__ proj_w,
                                                    const void* __restrict__ pb) {
  const bool pwf = arr_is_f32(proj_w);   // proj_b shares policy
  // XCD swizzle matching attn's window->XCD mapping (2160 = 8*270, bijective)
  const int i0 = blockIdx.x;
  const int ii = (i0 & 7) * 270 + (i0 >> 3);
  const int tid = threadIdx.x;
  const int lane = tid & 63, wv = tid >> 6;
  const int l15 = lane & 15, lg = lane >> 4;
  const size_t row0 = (size_t)ii * 64 + wv * 16;

  // B-fragments: activation rows (f32 -> bf16), B[col=t][k]: t=l15, k=lg*8+j
  short8 bfr[6];
  {
    const float* xp = io + (row0 + l15) * CC + lg * 8;
#pragma unroll
    for (int kk = 0; kk < 6; ++kk) {
      fvec4 a = *(const fvec4*)(xp + kk * 32);
      fvec4 b = *(const fvec4*)(xp + kk * 32 + 4);
      union { uint4 u; short8 s; } cv;
      cv.u = make_uint4(pack2(a[0], a[1]), pack2(a[2], a[3]),
                        pack2(b[0], b[1]), pack2(b[2], b[3]));
      bfr[kk] = cv.s;
    }
  }
  fvec4 acc[12];
#pragma unroll
  for (int nt = 0; nt < 12; ++nt) {
    if (pwf) {
      acc[nt] = *(const fvec4*)((const float*)pb + nt * 16 + lg * 4);
    } else {
      const ushort* p = (const ushort*)pb + nt * 16 + lg * 4;
      acc[nt][0] = bf2f(p[0]); acc[nt][1] = bf2f(p[1]);
      acc[nt][2] = bf2f(p[2]); acc[nt][3] = bf2f(p[3]);
    }
  }
  const short8* wf8 = (const short8*)g_PF;
#pragma unroll
  for (int kk = 0; kk < 6; ++kk)
#pragma unroll
    for (int nt = 0; nt < 12; ++nt)
      acc[nt] = __builtin_amdgcn_mfma_f32_16x16x32_bf16(wf8[(kk * 12 + nt) * 64 + lane], bfr[kk], acc[nt], 0, 0, 0);
  // store: io[row0+l15][c = nt*16+lg*4+r]  (vectorized, own rows only)
  float* op = io + (row0 + l15) * CC + lg * 4;
#pragma unroll
  for (int nt = 0; nt < 12; ++nt)
    *(fvec4*)(op + nt * 16) = acc[nt];
}

// ---------------------------------------------------------------------------
extern "C" void kernel_launch(void* const* d_in, const int* in_sizes, int n_in,
                              void* d_out, int out_size, void* d_ws, size_t ws_size,
                              hipStream_t stream) {
  const void *x = d_in[0], *mask = d_in[1], *qkv_w = d_in[2], *qkv_b = d_in[3],
             *proj_w = d_in[4], *proj_b = d_in[5], *bias_tab = d_in[6];
  for (int i = 0; i < n_in; ++i) {
    switch (in_sizes[i]) {
      case 26542080: x = d_in[i]; break;
      case 19906560: mask = d_in[i]; break;
      case 110592:   qkv_w = d_in[i]; break;
      case 576:      qkv_b = d_in[i]; break;
      case 36864:    proj_w = d_in[i]; break;
      case 192:      proj_b = d_in[i]; break;
      case 1271808:  bias_tab = d_in[i]; break;
      default: break;
    }
  }
  float* out = (float*)d_out;
  prep_w<<<144, 256, 0, stream>>>(qkv_w, proj_w);
  prep_bc<<<69, 256, 0, stream>>>(bias_tab);
  attn_mfma<<<NH * NW * NLON, 576, 0, stream>>>(x, qkv_w, qkv_b, mask, out);
  proj_mfma<<<TT / 64, 256, 0, stream>>>(out, proj_w, proj_b);
}

// Round 6
// 544.595 us; speedup vs baseline: 1.1125x; 1.1125x over previous
//
#include <hip/hip_runtime.h>
#include <hip/hip_bf16.h>

typedef __attribute__((ext_vector_type(8))) short short8;
typedef __attribute__((ext_vector_type(4))) float fvec4;

#define NW 64
#define NN 144
#define CC 192
#define NH 6
#define LL 32
#define NLON 15
#define TT (NLON*NW*NN)   // 138240

// Pre-transformed weights in device-global memory (written by prep kernels).
__device__ ushort g_WF[6 * 36 * 512];    // per-head frag-linear qkv W (q rows prescaled by 1/sqrt32)
__device__ ushort g_PF[6 * 12 * 512];    // frag-linear proj W          [kk6][nt12][lane][8]
__device__ __align__(4) ushort g_BC[64 * 6 * 3312];   // bias_table transposed [w][h][epi]
__device__ float  g_QB[6 * 96];          // per-head qkv bias (q part prescaled)
__device__ int    g_mflag;               // nonzero if mask has any nonzero bits

__device__ __forceinline__ float bf2f(ushort v) {
  union { unsigned int u; float f; } x;
  x.u = ((unsigned int)v) << 16;
  return x.f;
}
__device__ __forceinline__ ushort f2bf(float f) {
  union { float f; unsigned int u; } x; x.f = f;
  unsigned int r = (x.u + 0x7FFFu + ((x.u >> 16) & 1u)) >> 16;
  return (ushort)r;
}
// packed f32x2 -> bf16x2 (compiler emits v_cvt_pk_bf16_f32; RNE, matches f2bf)
__device__ __forceinline__ uint pack2(float a, float b) {
  __hip_bfloat162 t = __float22bfloat162_rn(make_float2(a, b));
  uint u; __builtin_memcpy(&u, &t, 4); return u;
}

// Robust dtype detector (needs arrays >= ~16KB; only used on large arrays).
__device__ bool arr_is_f32(const void* p) {
  const ushort* u = (const ushort*)p;
  int sane = 0;
#pragma unroll
  for (int k = 0; k < 16; ++k) {
    float v = bf2f(u[k * 514]);
    if (__builtin_fabsf(v) < 64.f) ++sane;
  }
  return sane < 16;
}
__device__ __forceinline__ float loadS(const void* p, size_t i, bool f) {
  return f ? ((const float*)p)[i] : bf2f(((const ushort*)p)[i]);
}

// ---------------------------------------------------------------------------
// prep_w: one-time weight reorganization + bias vector. Idempotent.
__global__ __launch_bounds__(256) void prep_w(const void* __restrict__ qkv_w,
                                              const void* __restrict__ proj_w,
                                              const void* __restrict__ qkv_b) {
  const bool wf = arr_is_f32(qkv_w);     // qkv_b shares policy
  const bool pwf = arr_is_f32(proj_w);
  if (blockIdx.x == 0 && threadIdx.x == 0) g_mflag = 0;
  const int stride = gridDim.x * blockDim.x;
  const int t0 = blockIdx.x * blockDim.x + threadIdx.x;
  const float scale = 0.17677669529663687f;   // 1/sqrt(32)
  // WF: B-frag for (h,kk,nt): row c=nt*16+(lane&15), k=kk*32+(lane>>4)*8+j.
  // q rows (nt<2) prescaled so attn needs no scale op.
  for (int i = t0; i < 6 * 36 * 512; i += stride) {
    int j = i & 7, lane = (i >> 3) & 63, f = i >> 9;   // f = h*36 + kk*6 + nt
    int nt = f % 6, kk = (f / 6) % 6, h = f / 36;
    int c = nt * 16 + (lane & 15);
    int k = kk * 32 + (lane >> 4) * 8 + j;
    int grow = (c >> 5) * 192 + h * 32 + (c & 31);
    float v = loadS(qkv_w, (size_t)grow * 192 + k, wf);
    if (nt < 2) v *= scale;
    g_WF[i] = f2bf(v);
  }
  // PF: row c = nt*16+(lane&15) of proj_w, k = kk*32+(lane>>4)*8+j
  for (int i = t0; i < 6 * 12 * 512; i += stride) {
    int j = i & 7, lane = (i >> 3) & 63, f = i >> 9;   // f = kk*12 + nt
    int nt = f % 12, kk = f / 12;
    int c = nt * 16 + (lane & 15);
    int k = kk * 32 + (lane >> 4) * 8 + j;
    g_PF[i] = f2bf(loadS(proj_w, (size_t)c * 192 + k, pwf));
  }
  // QB: per-head bias, q part prescaled. g_QB[h*96 + c]
  for (int i = t0; i < 6 * 96; i += stride) {
    int h = i / 96, c = i - h * 96;
    float v = loadS(qkv_b, (c >> 5) * 192 + h * 32 + (c & 31), wf);
    if (c < 32) v *= scale;
    g_QB[i] = v;
  }
}

// ---------------------------------------------------------------------------
// prep_bc: LDS-tiled transpose g_BC[wh][e] <- bt[e][wh]; both sides coalesced.
__global__ __launch_bounds__(256) void prep_bc(const void* __restrict__ bt) {
  __shared__ ushort T[48 * 386];               // +2-ushort pad: bank-spread reads
  const bool bf = arr_is_f32(bt);
  const int e0 = blockIdx.x * 48;
  const int tid = threadIdx.x;
  for (int idx = tid; idx < 48 * 384; idx += 256) {
    int de = idx / 384, wh = idx - de * 384;   // consecutive tid -> consecutive wh
    T[de * 386 + wh] = f2bf(loadS(bt, (size_t)(e0 + de) * 384 + wh, bf));
  }
  __syncthreads();
  for (int idx = tid; idx < 48 * 384; idx += 256) {
    int wh = idx / 48, e2 = idx - wh * 48;     // consecutive tid -> consecutive e
    g_BC[(size_t)wh * 3312 + e0 + e2] = T[e2 * 386 + wh];
  }
}

// ---------------------------------------------------------------------------
// mask_probe: set g_mflag if mask has any nonzero bits (lets attn skip all
// mask loads for the common all-zero mask; correct for any input).
__global__ __launch_bounds__(256) void mask_probe(const void* __restrict__ mask) {
  const bool mf = arr_is_f32(mask);
  const size_t n16 = ((size_t)TT * NN * (mf ? 4 : 2)) >> 4;
  const uint4* p = (const uint4*)mask;
  uint acc = 0;
  for (size_t i = (size_t)blockIdx.x * blockDim.x + threadIdx.x;
       i < n16; i += (size_t)gridDim.x * blockDim.x) {
    uint4 v = p[i];
    acc |= v.x | v.y | v.z | v.w;
  }
  if (__any(acc != 0) && (threadIdx.x & 63) == 0) atomicOr(&g_mflag, 1);
}

// ---------------------------------------------------------------------------
// MFMA fused QKV + attention. One block per (b,w,h); 9 waves, 16 queries each.
// Phase 1: q/k computed operand-SWAPPED (mfma(W,x): D rows=channels) so each
// thread's 4 values are LDS-contiguous -> ds_write_b64; bias+scale folded into
// the MFMA C-operand (g_QB / prescaled g_WF). v keeps mfma(x,W) (token-per-r
// makes its vT writes contiguous).
// Phase 2 (swapped qk): thread owns query col n=wv*16+l15, key rows
// {m:(m&15)>>2==lg}; softmax reduces over the 4-lane group (shfl 16|32).
// Bias gathers moved L1 -> LDS (bcl): round-5's 36 divergent L1 gathers/thread
// were the VMEM-pipe serializer. em[m+r]=em[m]-r (4-runs never cross h2/z2).
// LDS map (35872 B, 3 blocks/CU by LDS & waves):
//  [0,9216)      qF [9 wave][64][16B]; wave's own slot = P scratch in phase 2
//  [9216,18432)  kF [9 tile][64][16B]
//  [18432,28672) vF [10 blk][64][16B], key tokens 144..159 zeroed
//  [28672,35296) bcl ushort[3312] bias row for (w,h)
//  [35296,35872) em  int[144]
__global__ __launch_bounds__(576, 5) void attn_mfma(
    const void* __restrict__ x, const void* __restrict__ mask,
    float* __restrict__ out) {
  __shared__ __attribute__((aligned(16))) char lds[35872];
  const bool xf = arr_is_f32(x);
  const bool use_mask = (g_mflag != 0);
  // XCD-chunked swizzle: 5760 blocks, 8 XCDs, 720/chunk; h-fastest per chunk.
  const int i0 = blockIdx.x;
  const int ii = (i0 & 7) * 720 + (i0 >> 3);
  const int h = ii % 6;
  const int g0 = ii / 6;
  const int w = g0 & 63, bb = g0 >> 6;
  const int tid = threadIdx.x;
  const int lane = tid & 63, wv = tid >> 6;
  const int l15 = lane & 15, lg = lane >> 4;
  const size_t tok0 = ((size_t)bb * NW + w) * NN;

  // ---- preload x B-fragments (tokens of this wave's strip)
  short8 afr[6];
  {
    const size_t xrow = (tok0 + wv * 16 + l15) * CC + lg * 8;
    if (xf) {
      const float* xp = (const float*)x + xrow;
#pragma unroll
      for (int kk = 0; kk < 6; ++kk) {
        fvec4 a = *(const fvec4*)(xp + kk * 32);
        fvec4 b = *(const fvec4*)(xp + kk * 32 + 4);
        union { uint4 u; short8 s; } cv;
        cv.u = make_uint4(pack2(a[0], a[1]), pack2(a[2], a[3]),
                          pack2(b[0], b[1]), pack2(b[2], b[3]));
        afr[kk] = cv.s;
      }
    } else {
      const ushort* xp = (const ushort*)x + xrow;
#pragma unroll
      for (int kk = 0; kk < 6; ++kk) afr[kk] = *(const short8*)(xp + kk * 32);
    }
  }
  // ---- stage bias row (6624B, coalesced), zero vT tail, build em table
  {
    const uint* src = (const uint*)(g_BC + (size_t)(w * 6 + h) * 3312);
    uint* dst = (uint*)(lds + 28672);
    for (int i = tid; i < 1656; i += 576) dst[i] = src[i];
  }
  if (tid < 256) {
    int half = tid >> 7, off = tid & 127;
    ((uint*)(lds + 18432 + (8 + half) * 1024 + 512))[off] = 0;
  }
  if (tid < 144) {
    int z2 = tid / 72, r2 = tid - z2 * 72;
    int h2 = r2 / 12, w2 = r2 - h2 * 12;
    ((int*)(lds + 35296))[tid] = 1656 * z2 + 138 * h2 - w2;
  }

  // ---- phase 1: QKV GEMM, 36 MFMAs/wave; C-operand = bias (pre-scaled)
  const float* qb = g_QB + h * 96;
  fvec4 acc[6];
#pragma unroll
  for (int nt = 0; nt < 4; ++nt)
    acc[nt] = *(const fvec4*)(qb + nt * 16 + lg * 4);       // rows = channels
#pragma unroll
  for (int nt = 4; nt < 6; ++nt) {
    float bv = qb[nt * 16 + l15];                           // cols = channels
    acc[nt] = (fvec4){bv, bv, bv, bv};
  }
  {
    const short8* WFp = (const short8*)g_WF + (size_t)h * 36 * 64;
#pragma unroll
    for (int kk = 0; kk < 6; ++kk) {
#pragma unroll
      for (int nt = 0; nt < 6; ++nt) {
        short8 wb = WFp[(kk * 6 + nt) * 64 + lane];
        acc[nt] = (nt < 4)
          ? __builtin_amdgcn_mfma_f32_16x16x32_bf16(wb, afr[kk], acc[nt], 0, 0, 0)
          : __builtin_amdgcn_mfma_f32_16x16x32_bf16(afr[kk], wb, acc[nt], 0, 0, 0);
      }
    }
  }
  // q/k: thread holds channels (nt*16+lg*4+r), token l15 -> one b64 per nt
#pragma unroll
  for (int nt = 0; nt < 4; ++nt) {
    int dim = (nt & 1) * 16 + lg * 4;
    char* base = lds + (nt < 2 ? 0 : 9216) + wv * 1024;
    uint2 pv2 = make_uint2(pack2(acc[nt][0], acc[nt][1]),
                           pack2(acc[nt][2], acc[nt][3]));
    *(uint2*)(base + ((dim >> 3) << 8) + (l15 << 4) + ((dim & 7) << 1)) = pv2;
  }
  // v: thread holds tokens (wv*16+lg*4+r), channel l15 -> one b64 per nt
#pragma unroll
  for (int nt = 4; nt < 6; ++nt) {
    uint2 pv2 = make_uint2(pack2(acc[nt][0], acc[nt][1]),
                           pack2(acc[nt][2], acc[nt][3]));
    int blk = (wv >> 1) * 2 + (nt - 4);
    int t34 = (wv * 2 + (lg >> 1)) & 3;
    *(uint2*)(lds + 18432 + (blk << 10) + (t34 << 8) + (l15 << 4) + ((lg & 1) << 3)) = pv2;
  }
  __syncthreads();   // the only barrier

  // ---- phase 2: thread owns query col n = wv*16 + l15
  const short8* qf8 = (const short8*)lds;
  const short8* kf8 = (const short8*)(lds + 9216);
  const short8* vf8 = (const short8*)(lds + 18432);
  const ushort* bcl = (const ushort*)(lds + 28672);
  const int* emt = (const int*)(lds + 35296);
  short8 qfr = qf8[wv * 64 + lane];          // own q slot now dead -> P scratch

  const int n_glob = wv * 16 + l15;
  int en;
  {
    int z1 = n_glob / 72, r1 = n_glob - z1 * 72;
    int h1 = r1 / 12, w1 = r1 - h1 * 12;
    en = 828 * z1 + 23 * h1 + w1 + 11;
  }
  const size_t mrow = (tok0 + n_glob) * (size_t)NN;

  // all 9 S^T tiles, single pass (full ILP). C = bias (+mask if any).
  fvec4 s[9];
#pragma unroll
  for (int mt = 0; mt < 9; ++mt) {
    int e0 = en + emt[mt * 16 + lg * 4];     // em[m+r] = em[m]-r
    fvec4 cc;
    cc[0] = bf2f(bcl[e0]);
    cc[1] = bf2f(bcl[e0 - 1]);
    cc[2] = bf2f(bcl[e0 - 2]);
    cc[3] = bf2f(bcl[e0 - 3]);
    if (use_mask) {
      if (xf) {
        fvec4 mk = *(const fvec4*)((const float*)mask + mrow + mt * 16 + lg * 4);
#pragma unroll
        for (int r = 0; r < 4; ++r) cc[r] += mk[r];
      } else {
        const ushort* mp = (const ushort*)mask + mrow + mt * 16 + lg * 4;
#pragma unroll
        for (int r = 0; r < 4; ++r) cc[r] += bf2f(mp[r]);
      }
    }
    s[mt] = __builtin_amdgcn_mfma_f32_16x16x32_bf16(kf8[mt * 64 + lane], qfr, cc, 0, 0, 0);
  }
  // single-pass softmax; rows split over the 4-lane group -> shfl 16|32
  fvec4 mv = s[0];
#pragma unroll
  for (int mt = 1; mt < 9; ++mt)
#pragma unroll
    for (int r = 0; r < 4; ++r) mv[r] = fmaxf(mv[r], s[mt][r]);
  float mx = fmaxf(fmaxf(mv[0], mv[1]), fmaxf(mv[2], mv[3]));
  mx = fmaxf(mx, __shfl_xor(mx, 16));
  mx = fmaxf(mx, __shfl_xor(mx, 32));
  float sum = 0.f;
  uint pw[20];
#pragma unroll
  for (int mt = 0; mt < 9; ++mt) {
    fvec4 e;
#pragma unroll
    for (int r = 0; r < 4; ++r) { e[r] = __expf(s[mt][r] - mx); sum += e[r]; }
    pw[2 * mt]     = pack2(e[0], e[1]);
    pw[2 * mt + 1] = pack2(e[2], e[3]);
  }
  pw[18] = 0; pw[19] = 0;                    // key tokens 144..159
  // PV: serial same-slot P scratch (DS in-order => write->read safe)
  char* ps = lds + wv * 1024;
  const int wo0 = ((((lg >> 1)) * 16 + l15) << 4) + ((lg & 1) << 3);
  const int wo1 = ((((lg >> 1) + 2) * 16 + l15) << 4) + ((lg & 1) << 3);
  fvec4 o0 = {0.f, 0.f, 0.f, 0.f}, o1 = {0.f, 0.f, 0.f, 0.f};
#pragma unroll
  for (int tk = 0; tk < 5; ++tk) {
    *(uint2*)(ps + wo0) = make_uint2(pw[4 * tk + 0], pw[4 * tk + 1]);
    *(uint2*)(ps + wo1) = make_uint2(pw[4 * tk + 2], pw[4 * tk + 3]);
    short8 pfr = *(const short8*)(ps + lane * 16);
    o0 = __builtin_amdgcn_mfma_f32_16x16x32_bf16(vf8[(tk * 2 + 0) * 64 + lane], pfr, o0, 0, 0, 0);
    o1 = __builtin_amdgcn_mfma_f32_16x16x32_bf16(vf8[(tk * 2 + 1) * 64 + lane], pfr, o1, 0, 0, 0);
  }
  // epilogue: group-reduced denominator, normalize, vectorized store
  sum += __shfl_xor(sum, 16);
  sum += __shfl_xor(sum, 32);
  float inv = 1.f / sum;
  fvec4 r0, r1;
#pragma unroll
  for (int r = 0; r < 4; ++r) { r0[r] = o0[r] * inv; r1[r] = o1[r] * inv; }
  float* op = out + (tok0 + n_glob) * CC + h * LL + lg * 4;
  *(fvec4*)op = r0;
  *(fvec4*)(op + 16) = r1;
}

// ---------------------------------------------------------------------------
// MFMA in-place projection, swapped operands; pipelined per-kk activation
// loads keep live regs ~72 (insurance against spill at cap 102).
__global__ __launch_bounds__(256, 5) void proj_mfma(float* __restrict__ io,
                                                    const void* __restrict__ proj_w,
                                                    const void* __restrict__ pb) {
  const bool pwf = arr_is_f32(proj_w);   // proj_b shares policy
  const int i0 = blockIdx.x;
  const int ii = (i0 & 7) * 270 + (i0 >> 3);   // XCD swizzle (2160 = 8*270)
  const int tid = threadIdx.x;
  const int lane = tid & 63, wv = tid >> 6;
  const int l15 = lane & 15, lg = lane >> 4;
  const size_t row0 = (size_t)ii * 64 + wv * 16;

  fvec4 acc[12];
#pragma unroll
  for (int nt = 0; nt < 12; ++nt) {
    if (pwf) {
      acc[nt] = *(const fvec4*)((const float*)pb + nt * 16 + lg * 4);
    } else {
      const ushort* p = (const ushort*)pb + nt * 16 + lg * 4;
      acc[nt][0] = bf2f(p[0]); acc[nt][1] = bf2f(p[1]);
      acc[nt][2] = bf2f(p[2]); acc[nt][3] = bf2f(p[3]);
    }
  }
  const float* xp = io + (row0 + l15) * CC + lg * 8;
  const short8* wf8 = (const short8*)g_PF;
  fvec4 a0 = *(const fvec4*)(xp), b0 = *(const fvec4*)(xp + 4);
#pragma unroll
  for (int kk = 0; kk < 6; ++kk) {
    fvec4 an, bn;
    if (kk < 5) { an = *(const fvec4*)(xp + (kk + 1) * 32);
                  bn = *(const fvec4*)(xp + (kk + 1) * 32 + 4); }
    union { uint4 u; short8 s; } cv;
    cv.u = make_uint4(pack2(a0[0], a0[1]), pack2(a0[2], a0[3]),
                      pack2(b0[0], b0[1]), pack2(b0[2], b0[3]));
#pragma unroll
    for (int nt = 0; nt < 12; ++nt)
      acc[nt] = __builtin_amdgcn_mfma_f32_16x16x32_bf16(wf8[(kk * 12 + nt) * 64 + lane], cv.s, acc[nt], 0, 0, 0);
    a0 = an; b0 = bn;
  }
  float* op = io + (row0 + l15) * CC + lg * 4;
#pragma unroll
  for (int nt = 0; nt < 12; ++nt)
    *(fvec4*)(op + nt * 16) = acc[nt];
}

// ---------------------------------------------------------------------------
extern "C" void kernel_launch(void* const* d_in, const int* in_sizes, int n_in,
                              void* d_out, int out_size, void* d_ws, size_t ws_size,
                              hipStream_t stream) {
  const void *x = d_in[0], *mask = d_in[1], *qkv_w = d_in[2], *qkv_b = d_in[3],
             *proj_w = d_in[4], *proj_b = d_in[5], *bias_tab = d_in[6];
  for (int i = 0; i < n_in; ++i) {
    switch (in_sizes[i]) {
      case 26542080: x = d_in[i]; break;
      case 19906560: mask = d_in[i]; break;
      case 110592:   qkv_w = d_in[i]; break;
      case 576:      qkv_b = d_in[i]; break;
      case 36864:    proj_w = d_in[i]; break;
      case 192:      proj_b = d_in[i]; break;
      case 1271808:  bias_tab = d_in[i]; break;
      default: break;
    }
  }
  float* out = (float*)d_out;
  prep_w<<<144, 256, 0, stream>>>(qkv_w, proj_w, qkv_b);
  prep_bc<<<69, 256, 0, stream>>>(bias_tab);
  mask_probe<<<1024, 256, 0, stream>>>(mask);
  attn_mfma<<<NH * NW * NLON, 576, 0, stream>>>(x, mask, out);
  proj_mfma<<<TT / 64, 256, 0, stream>>>(out, proj_w, proj_b);
}